// Round 15
// baseline (2297.252 us; speedup 1.0000x reference)
//
#include <hip/hip_runtime.h>

typedef _Float16 f16;
typedef _Float16 f16x8 __attribute__((ext_vector_type(8)));
typedef _Float16 f16x4 __attribute__((ext_vector_type(4)));
typedef float f32x4 __attribute__((ext_vector_type(4)));

#define MFMA16(a, b, c) __builtin_amdgcn_mfma_f32_16x16x32_f16(a, b, c, 0, 0, 0)

#define CH 16         // steps per chunk (model-optimal for the proven protocol)
#define NCH 32        // chunks (512 steps)
#define SLOT_H (CH * 24 * 64 * 4)   // f16 elems per pre-ring slot = 98304

__device__ __forceinline__ float fast_tanh(float x) {
    float e = __builtin_amdgcn_exp2f(x * 2.885390081777927f);
    return 1.0f - 2.0f * __builtin_amdgcn_rcpf(e + 1.0f);
}

// LDS-only barrier: does NOT drain vmcnt (global stores keep flying)
__device__ __forceinline__ void lds_barrier() {
    asm volatile("s_waitcnt lgkmcnt(0)" ::: "memory");
    __builtin_amdgcn_s_barrier();
    __builtin_amdgcn_sched_barrier(0);
}

// ---- SETTLED PROTOCOL (9 experiments; benches 2,3,5,12,14 pass at best perf):
//   publish  = cached stores -> __syncthreads -> RELEASE agent atomic
//   consume  = RELAXED agent poll -> sc0sc1 LLC-direct data loads
__device__ __forceinline__ f16x8 ld_llc(const f16* p) {
    f16x8 v;
    asm volatile("global_load_dwordx4 %0, %1, off sc0 sc1" : "=v"(v) : "v"(p) : "memory");
    return v;
}
__device__ __forceinline__ f16x4 ld_llc_f16x4(const f16* p) {
    f16x4 v;
    asm volatile("global_load_dwordx2 %0, %1, off sc0 sc1" : "=v"(v) : "v"(p) : "memory");
    return v;
}

// counted vmcnt waits that REDEFINE the loaded regs (rule #18)
#define VWAIT4(N, x0, x1, x2, x3) \
    asm volatile("s_waitcnt vmcnt(" #N ")" : "+v"(x0), "+v"(x1), "+v"(x2), "+v"(x3))
#define VWAITH3(N, p0, p1, p2) \
    asm volatile("s_waitcnt vmcnt(" #N ")" : "+v"(p0), "+v"(p1), "+v"(p2))

// ---------------- flag sync (architected atomics only) ----------------
__device__ __forceinline__ void wait_flag(const int* f, int target) {
    if (threadIdx.x == 0) {
        while (__hip_atomic_load(f, __ATOMIC_RELAXED, __HIP_MEMORY_SCOPE_AGENT) < target) {
            __builtin_amdgcn_s_sleep(1);
        }
    }
    __syncthreads();
}
__device__ __forceinline__ void set_flag(int* f, int val) {
    __syncthreads();  // all waves' cached data stores complete (vmcnt drained)
    if (threadIdx.x == 0)
        __hip_atomic_store(f, val, __ATOMIC_RELEASE, __HIP_MEMORY_SCOPE_AGENT);
}

// ---------------- weight convert: f32 -> f16 ----------------
__global__ void cvt_kernel(const float* __restrict__ src, f16* __restrict__ dst, const int n4) {
    const int i = blockIdx.x * blockDim.x + threadIdx.x;
    if (i < n4) {
        const float4 v = ((const float4*)src)[i];
        f16x4 o = { (f16)v.x, (f16)v.y, (f16)v.z, (f16)v.w };
        *(f16x4*)(dst + (size_t)i * 4) = o;
    }
}

__global__ void bias_combine_kernel(const float* __restrict__ b_ih, const float* __restrict__ b_hh,
                                    float* __restrict__ bias_c) {
    const int i = blockIdx.x * blockDim.x + threadIdx.x;
    if (i < 6 * 384) bias_c[i] = b_ih[i] + b_hh[i];
}

// ---------------- embedding gather + cast ----------------
__global__ void embed_kernel(const int* __restrict__ x, const float* __restrict__ emb,
                             f16* __restrict__ seq0) {
    const int token = blockIdx.x;          // token = t*16 + b
    const int s = token >> 4, b = token & 15;
    const int idx = x[b * 512 + s];
    const float4 v = ((const float4*)(emb + (size_t)idx * 256))[threadIdx.x];
    f16x4 o = { (f16)v.x, (f16)v.y, (f16)v.z, (f16)v.w };
    *(f16x4*)(seq0 + (size_t)token * 256 + threadIdx.x * 4) = o;
}

// ---------------- A-role: input projection, 8 waves x 3 N-tiles ----------------
// Per-wave regs: WiF[3][NK<=12]=144 + a[12]=48 + acc=12 + addr ~= 230 < 256.
template<int NK>
__device__ __forceinline__ void a_role(const f16* __restrict__ in_seq,
                                       const f16* __restrict__ Wi,
                                       const float* __restrict__ bias,
                                       f16* __restrict__ preL,
                                       const int* flag_in, int* flag_pre, const int* flag_seq,
                                       const int L) {
    const int tid = threadIdx.x, lane = tid & 63, w = tid >> 6;   // w in [0,8)
    const int lr = lane & 15, lq = lane >> 4;
    const int KIN = NK * 32;

    f16x8 WiF[3][NK];
#pragma unroll
    for (int i = 0; i < 3; ++i) {
        const f16* wrow = Wi + (size_t)((w * 3 + i) * 16 + lr) * KIN + lq * 8;
#pragma unroll
        for (int kk = 0; kk < NK; ++kk) WiF[i][kk] = *(const f16x8*)(wrow + kk * 32);
    }
    float bv[3];
#pragma unroll
    for (int i = 0; i < 3; ++i) bv[i] = bias[(w * 3 + i) * 16 + lr];

    for (int c = 0; c < NCH; ++c) {
        if (L > 0) wait_flag(flag_in, c + 1);          // input chunk ready
        if (c >= 4) wait_flag(flag_seq, c - 3);        // ring back-pressure (4 slots)

        f16* slot = preL + (size_t)(c & 3) * SLOT_H;
#pragma unroll 1
        for (int sc = 0; sc < CH; ++sc) {
            const int t = c * CH + sc;
            f32x4 acc[3];
#pragma unroll
            for (int i = 0; i < 3; ++i) acc[i] = (f32x4){ bv[i], bv[i], bv[i], bv[i] };

            const f16* ar = in_seq + (size_t)(t * 16 + lr) * KIN + lq * 8;
            f16x8 a[NK];
#pragma unroll
            for (int kk = 0; kk < NK; ++kk) a[kk] = ld_llc(ar + kk * 32);
            if constexpr (NK == 12) {
                VWAIT4(8, a[0], a[1], a[2], a[3]);
#pragma unroll
                for (int kk = 0; kk < 4; ++kk)
#pragma unroll
                    for (int i = 0; i < 3; ++i) acc[i] = MFMA16(a[kk], WiF[i][kk], acc[i]);
                VWAIT4(4, a[4], a[5], a[6], a[7]);
#pragma unroll
                for (int kk = 4; kk < 8; ++kk)
#pragma unroll
                    for (int i = 0; i < 3; ++i) acc[i] = MFMA16(a[kk], WiF[i][kk], acc[i]);
                VWAIT4(0, a[8], a[9], a[10], a[11]);
#pragma unroll
                for (int kk = 8; kk < 12; ++kk)
#pragma unroll
                    for (int i = 0; i < 3; ++i) acc[i] = MFMA16(a[kk], WiF[i][kk], acc[i]);
            } else {
                VWAIT4(4, a[0], a[1], a[2], a[3]);
#pragma unroll
                for (int kk = 0; kk < 4; ++kk)
#pragma unroll
                    for (int i = 0; i < 3; ++i) acc[i] = MFMA16(a[kk], WiF[i][kk], acc[i]);
                VWAIT4(0, a[4], a[5], a[6], a[7]);
#pragma unroll
                for (int kk = 4; kk < 8; ++kk)
#pragma unroll
                    for (int i = 0; i < 3; ++i) acc[i] = MFMA16(a[kk], WiF[i][kk], acc[i]);
            }
            // f16 pre, CACHED store (release orders it); layout identical to r12
#pragma unroll
            for (int i = 0; i < 3; ++i) {
                f16x4 ph = { (f16)acc[i][0], (f16)acc[i][1], (f16)acc[i][2], (f16)acc[i][3] };
                *(f16x4*)(slot + ((size_t)(sc * 24 + w * 3 + i) * 64 + lane) * 4) = ph;
            }
        }
        set_flag(flag_pre, c + 1);
    }
}

// ---------------- B-role: recurrence, 8 waves x 3 N-tiles ----------------
// Per-wave regs: WhF[3][12]=144 + pr=24 + acc=12 + temps ~= 210 < 256.
__device__ __forceinline__ void b_role(const f16* __restrict__ preL,
                                       const f16* __restrict__ Wh,
                                       f16* __restrict__ out_seq,
                                       const int* flag_pre, int* flag_seq,
                                       f16 (*hbuf)[16][392]) {
    const int tid = threadIdx.x, lane = tid & 63, w = tid >> 6;   // w in [0,8)
    const int lr = lane & 15, lq = lane >> 4, kb = lq * 8;

    for (int i = tid; i < 2 * 16 * 392; i += 512) (&hbuf[0][0][0])[i] = (f16)0.0f;

    f16x8 WhF[3][12];
#pragma unroll
    for (int i = 0; i < 3; ++i) {
        const f16* wrow = Wh + (size_t)((w * 3 + i) * 16 + lr) * 384 + kb;
#pragma unroll
        for (int kk = 0; kk < 12; ++kk) WhF[i][kk] = *(const f16x8*)(wrow + kk * 32);
    }
    __syncthreads();

    // cooperative copy: 384 threads x 16 f16 (2 x f16x8) covers 16x384
    const bool docopy = (tid < 384);
    const int crow = tid / 24;
    const int ccol = (tid % 24) * 16;

    for (int c = 0; c < NCH; ++c) {
        wait_flag(flag_pre, c + 1);
        const f16* slot = preL + (size_t)(c & 3) * SLOT_H;

#pragma unroll 1
        for (int g = 0; g < CH / 4; ++g) {
            f16x4 pr[4][3];
#pragma unroll
            for (int s = 0; s < 4; ++s)
#pragma unroll
                for (int i = 0; i < 3; ++i)
                    pr[s][i] = ld_llc_f16x4(slot + ((size_t)((g * 4 + s) * 24 + w * 3 + i) * 64 + lane) * 4);
            VWAITH3(0, pr[0][0], pr[0][1], pr[0][2]);
            VWAITH3(0, pr[1][0], pr[1][1], pr[1][2]);
            VWAITH3(0, pr[2][0], pr[2][1], pr[2][2]);
            VWAITH3(0, pr[3][0], pr[3][1], pr[3][2]);

#pragma unroll
            for (int s4 = 0; s4 < 4; ++s4) {
                const int sc = g * 4 + s4;            // step within chunk
                const int t = c * CH + sc;            // t&1 == sc&1 (CH even)
                f32x4 acc[3];
#pragma unroll
                for (int i = 0; i < 3; ++i) acc[i] = (f32x4){ 0.f, 0.f, 0.f, 0.f };

                const f16* hb = &hbuf[sc & 1][0][0] + lr * 392 + kb;
#pragma unroll
                for (int kk = 0; kk < 12; ++kk) {
                    const f16x8 a = *(const f16x8*)(hb + kk * 32);
#pragma unroll
                    for (int i = 0; i < 3; ++i) acc[i] = MFMA16(a, WhF[i][kk], acc[i]);
                }

                f16* hn = &hbuf[(sc + 1) & 1][0][0];
#pragma unroll
                for (int i = 0; i < 3; ++i) {
                    const int n = (w * 3 + i) * 16 + lr;
#pragma unroll
                    for (int r = 0; r < 4; ++r) {
                        const float v = acc[i][r] + (float)pr[s4][i][r];
                        hn[(lq * 4 + r) * 392 + n] = (f16)fast_tanh(v);
                    }
                }
                lds_barrier();   // LDS-only: seq stores below keep flying
                if (docopy) {
                    const f16* hs = &hbuf[(sc + 1) & 1][0][0] + crow * 392 + ccol;
                    f16* og = out_seq + (size_t)(t * 16 + crow) * 384 + ccol;
                    *(f16x8*)(og) = *(const f16x8*)(hs);
                    *(f16x8*)(og + 8) = *(const f16x8*)(hs + 8);
                }
            }
        }
        set_flag(flag_seq, c + 1);   // barrier + RELEASE (orders the cached seq stores)
    }
}

// ---------------- persistent pipeline: 12 blocks x 512 thr (8 waves) ----------------
__global__ __launch_bounds__(512, 1) void pipeline_kernel(
    const f16* __restrict__ seq0, const f16* __restrict__ Wi0,
    const f16* __restrict__ WiR, const f16* __restrict__ WhAll,
    const float* __restrict__ biasAll, f16* __restrict__ sA, f16* __restrict__ sB,
    f16* __restrict__ preRing, int* __restrict__ flags) {
    __shared__ f16 hbuf[2][16][392];
    const int bid = blockIdx.x;
    // flags[0..5] = seq chunks published by layer l; flags[8..13] = pre chunks published
    if (bid < 6) {
        const int L = bid;
        const f16* in_seq = (L == 0) ? seq0 : ((L & 1) ? sA : sB);
        const f16* Wi = (L == 0) ? Wi0 : (WiR + (size_t)(L - 1) * 384 * 384);
        f16* preL = preRing + (size_t)L * 4 * SLOT_H;
        if (L == 0)
            a_role<8>(in_seq, Wi, biasAll, preL, nullptr, flags + 8, flags + 0, 0);
        else
            a_role<12>(in_seq, Wi, biasAll + L * 384, preL, flags + (L - 1), flags + 8 + L, flags + L, L);
    } else {
        const int L = bid - 6;
        f16* outb = (L & 1) ? sB : sA;
        b_role(preRing + (size_t)L * 4 * SLOT_H, WhAll + (size_t)L * 384 * 384, outb,
               flags + 8 + L, flags + L, hbuf);
    }
}

// ---------------- output projection: [8192x384] x [384x32000] + bias ----------------
// 1D grid 16000 = 64 bm x 250 bn, bijective XCD swizzle (bm fastest => Wout tile
// L2-resident). Double-buffered LDS (1 barrier/iter) + SWAPPED-operand MFMA
// (D rows = n) => f32x4 epilogue stores.
__global__ __launch_bounds__(256) void out_proj_kernel(
    const f16* __restrict__ A, const f16* __restrict__ Bm,
    const float* __restrict__ bias, float* __restrict__ C) {
    __shared__ f16 As[2][128][40];
    __shared__ f16 Bs[2][128][40];
    const int tid = threadIdx.x, lane = tid & 63, w = tid >> 6;
    const int lr = lane & 15, lq = lane >> 4;
    const int lin = blockIdx.x;
    const int swz = (lin & 7) * 2000 + (lin >> 3);
    const int bn = swz >> 6;    // 0..249
    const int bm = swz & 63;    // 0..63
    const int wm = w >> 1, wn = w & 1;

    f32x4 acc[4][4];   // [mi][ni]; D row-space = n (swapped operands)
#pragma unroll
    for (int i = 0; i < 4; ++i)
#pragma unroll
        for (int j = 0; j < 4; ++j) acc[i][j] = (f32x4){ 0.f, 0.f, 0.f, 0.f };

    const int sr = tid >> 1, sh = tid & 1;
    const f16* Ag = A + (size_t)(bm * 128 + sr) * 384 + sh * 16;
    const f16* Bg = Bm + (size_t)(bn * 128 + sr) * 384 + sh * 16;

    // prologue: load kt=0 tile to regs
    f16x8 a0 = *(const f16x8*)(Ag);
    f16x8 a1 = *(const f16x8*)(Ag + 8);
    f16x8 b0 = *(const f16x8*)(Bg);
    f16x8 b1 = *(const f16x8*)(Bg + 8);

#pragma unroll 1
    for (int kt = 0; kt < 12; ++kt) {
        const int cur = kt & 1;
        *(f16x8*)(&As[cur][sr][sh * 16]) = a0;
        *(f16x8*)(&As[cur][sr][sh * 16 + 8]) = a1;
        *(f16x8*)(&Bs[cur][sr][sh * 16]) = b0;
        *(f16x8*)(&Bs[cur][sr][sh * 16 + 8]) = b1;
        if (kt < 11) {   // issue next tile's global loads; land after the barrier
            a0 = *(const f16x8*)(Ag + (kt + 1) * 32);
            a1 = *(const f16x8*)(Ag + (kt + 1) * 32 + 8);
            b0 = *(const f16x8*)(Bg + (kt + 1) * 32);
            b1 = *(const f16x8*)(Bg + (kt + 1) * 32 + 8);
        }
        __syncthreads();   // single barrier per iteration (double-buffered LDS)
        f16x8 af[4], bf[4];
#pragma unroll
        for (int mi = 0; mi < 4; ++mi) af[mi] = *(const f16x8*)(&As[cur][wm * 64 + mi * 16 + lr][lq * 8]);
#pragma unroll
        for (int ni = 0; ni < 4; ++ni) bf[ni] = *(const f16x8*)(&Bs[cur][wn * 64 + ni * 16 + lr][lq * 8]);
#pragma unroll
        for (int mi = 0; mi < 4; ++mi)
#pragma unroll
            for (int ni = 0; ni < 4; ++ni)
                acc[mi][ni] = MFMA16(bf[ni], af[mi], acc[mi][ni]);   // SWAPPED: rows=n
    }

    f32x4 bvv[4];
#pragma unroll
    for (int ni = 0; ni < 4; ++ni)
        bvv[ni] = *(const f32x4*)(bias + bn * 128 + wn * 64 + ni * 16 + lq * 4);
#pragma unroll
    for (int mi = 0; mi < 4; ++mi) {
        const int m = bm * 128 + wm * 64 + mi * 16 + lr;   // token = s*16+b
        const int s = m >> 4, b = m & 15;
        float* crow = C + (size_t)(b * 512 + s) * 32000;
#pragma unroll
        for (int ni = 0; ni < 4; ++ni) {
            const int n = bn * 128 + wn * 64 + ni * 16 + lq * 4;
            f32x4 o = acc[mi][ni] + bvv[ni];
            *(f32x4*)(crow + n) = o;
        }
    }
}

extern "C" void kernel_launch(void* const* d_in, const int* in_sizes, int n_in,
                              void* d_out, int out_size, void* d_ws, size_t ws_size,
                              hipStream_t stream) {
    const int* x = (const int*)d_in[0];
    const float* emb = (const float*)d_in[1];
    const float* W_ih0 = (const float*)d_in[2];
    const float* W_ih = (const float*)d_in[3];
    const float* W_hh = (const float*)d_in[4];
    const float* b_ih = (const float*)d_in[5];
    const float* b_hh = (const float*)d_in[6];
    const float* W_out = (const float*)d_in[7];
    const float* b_out = (const float*)d_in[8];
    float* out = (float*)d_out;

    // workspace layout (bytes)
    char* ws = (char*)d_ws;
    f16* Wi0_h = (f16*)(ws + 0);              //   384*256*2 = 196608
    f16* Wi_h = (f16*)(ws + 196608);          // 5*384*384*2 = 1474560
    f16* Wh_h = (f16*)(ws + 1671168);         // 6*384*384*2 = 1769472
    f16* Wout_h = (f16*)(ws + 3440640);       // 32000*384*2 = 24576000
    float* bias_c = (float*)(ws + 28016640);  // 6*384*4 = 9216
    f16* seq0 = (f16*)(ws + 28025856);        // 8192*256*2 = 4194304
    f16* sA = (f16*)(ws + 32220160);          // 8192*384*2 = 6291456
    f16* sB = (f16*)(ws + 38511616);          // 8192*384*2 = 6291456
    f16* preRing = (f16*)(ws + 44803072);     // 6*4*98304*2 = 4718592
    int* flags = (int*)(ws + 49521664);       // 256 -> end 49521920
    if (ws_size < 49521920u) return;

    hipMemsetAsync(flags, 0, 256, stream);
    cvt_kernel<<<96, 256, 0, stream>>>(W_ih0, Wi0_h, 24576);
    cvt_kernel<<<720, 256, 0, stream>>>(W_ih, Wi_h, 184320);
    cvt_kernel<<<864, 256, 0, stream>>>(W_hh, Wh_h, 221184);
    cvt_kernel<<<12000, 256, 0, stream>>>(W_out, Wout_h, 3072000);
    bias_combine_kernel<<<9, 256, 0, stream>>>(b_ih, b_hh, bias_c);
    embed_kernel<<<8192, 64, 0, stream>>>(x, emb, seq0);

    pipeline_kernel<<<12, 512, 0, stream>>>(seq0, Wi0_h, Wi_h, Wh_h, bias_c,
                                            sA, sB, preRing, flags);

    out_proj_kernel<<<16000, 256, 0, stream>>>(sB, Wout_h, b_out, out);
}

// Round 17
// 1653.754 us; speedup vs baseline: 1.3891x; 1.3891x over previous
//
#include <hip/hip_runtime.h>

typedef _Float16 f16;
typedef _Float16 f16x8 __attribute__((ext_vector_type(8)));
typedef _Float16 f16x4 __attribute__((ext_vector_type(4)));
typedef float f32x4 __attribute__((ext_vector_type(4)));

#define MFMA16(a, b, c) __builtin_amdgcn_mfma_f32_16x16x32_f16(a, b, c, 0, 0, 0)

#define CH 16         // steps per chunk (model-optimal for the proven protocol)
#define NCH 32        // chunks (512 steps)
#define SLOT_H (CH * 24 * 64 * 4)   // f16 elems per pre-ring slot = 98304

__device__ __forceinline__ float fast_tanh(float x) {
    float e = __builtin_amdgcn_exp2f(x * 2.885390081777927f);
    return 1.0f - 2.0f * __builtin_amdgcn_rcpf(e + 1.0f);
}

// LDS-only barrier: does NOT drain vmcnt (global stores keep flying)
__device__ __forceinline__ void lds_barrier() {
    asm volatile("s_waitcnt lgkmcnt(0)" ::: "memory");
    __builtin_amdgcn_s_barrier();
    __builtin_amdgcn_sched_barrier(0);
}

// ---- SETTLED PROTOCOL (9 experiments; benches 2,3,5,12,14 pass at best perf):
//   publish  = cached stores -> __syncthreads -> RELEASE agent atomic
//   consume  = RELAXED agent poll -> sc0sc1 LLC-direct data loads
__device__ __forceinline__ f16x8 ld_llc(const f16* p) {
    f16x8 v;
    asm volatile("global_load_dwordx4 %0, %1, off sc0 sc1" : "=v"(v) : "v"(p) : "memory");
    return v;
}
__device__ __forceinline__ f16x4 ld_llc_f16x4(const f16* p) {
    f16x4 v;
    asm volatile("global_load_dwordx2 %0, %1, off sc0 sc1" : "=v"(v) : "v"(p) : "memory");
    return v;
}

// counted vmcnt waits that REDEFINE the loaded regs (rule #18) — r14-proven
#define VWAIT4(N, x0, x1, x2, x3) \
    asm volatile("s_waitcnt vmcnt(" #N ")" : "+v"(x0), "+v"(x1), "+v"(x2), "+v"(x3))
#define VWAITH6(N, p0, p1, p2, p3, p4, p5) \
    asm volatile("s_waitcnt vmcnt(" #N ")" : "+v"(p0), "+v"(p1), "+v"(p2), "+v"(p3), "+v"(p4), "+v"(p5))

// ---------------- flag sync (architected atomics only) ----------------
__device__ __forceinline__ void wait_flag(const int* f, int target) {
    if (threadIdx.x == 0) {
        while (__hip_atomic_load(f, __ATOMIC_RELAXED, __HIP_MEMORY_SCOPE_AGENT) < target) {
            __builtin_amdgcn_s_sleep(1);
        }
    }
    __syncthreads();
}
__device__ __forceinline__ void set_flag(int* f, int val) {
    __syncthreads();  // all waves' cached data stores complete (vmcnt drained)
    if (threadIdx.x == 0)
        __hip_atomic_store(f, val, __ATOMIC_RELEASE, __HIP_MEMORY_SCOPE_AGENT);
}

// ---------------- weight convert: f32 -> f16 ----------------
__global__ void cvt_kernel(const float* __restrict__ src, f16* __restrict__ dst, const int n4) {
    const int i = blockIdx.x * blockDim.x + threadIdx.x;
    if (i < n4) {
        const float4 v = ((const float4*)src)[i];
        f16x4 o = { (f16)v.x, (f16)v.y, (f16)v.z, (f16)v.w };
        *(f16x4*)(dst + (size_t)i * 4) = o;
    }
}

__global__ void bias_combine_kernel(const float* __restrict__ b_ih, const float* __restrict__ b_hh,
                                    float* __restrict__ bias_c) {
    const int i = blockIdx.x * blockDim.x + threadIdx.x;
    if (i < 6 * 384) bias_c[i] = b_ih[i] + b_hh[i];
}

// ---------------- embedding gather + cast ----------------
__global__ void embed_kernel(const int* __restrict__ x, const float* __restrict__ emb,
                             f16* __restrict__ seq0) {
    const int token = blockIdx.x;          // token = t*16 + b
    const int s = token >> 4, b = token & 15;
    const int idx = x[b * 512 + s];
    const float4 v = ((const float4*)(emb + (size_t)idx * 256))[threadIdx.x];
    f16x4 o = { (f16)v.x, (f16)v.y, (f16)v.z, (f16)v.w };
    *(f16x4*)(seq0 + (size_t)token * 256 + threadIdx.x * 4) = o;
}

// ---------------- A-role: input projection, Wi register-resident ----------------
// SWAPPED MFMA (A-operand = W): D rows = n. acc[i][r] = pre[n=tile*16+lq*4+r][b=lr].
// Blob addresses identical to r14; content transposed consistently with B-role.
template<int NK>
__device__ __forceinline__ void a_role(const f16* __restrict__ in_seq,
                                       const f16* __restrict__ Wi,
                                       const float* __restrict__ bias,
                                       f16* __restrict__ preL,
                                       const int* flag_in, int* flag_pre, const int* flag_seq,
                                       const int L) {
    const int tid = threadIdx.x, lane = tid & 63, w = tid >> 6;
    const int lr = lane & 15, lq = lane >> 4;
    const int KIN = NK * 32;

    f16x8 WiF[6][NK];
#pragma unroll
    for (int i = 0; i < 6; ++i) {
        const f16* wrow = Wi + (size_t)((w * 6 + i) * 16 + lr) * KIN + lq * 8;
#pragma unroll
        for (int kk = 0; kk < NK; ++kk) WiF[i][kk] = *(const f16x8*)(wrow + kk * 32);
    }
    f32x4 bvv[6];   // bias along n (lq*4 + r) — same for every lane lr
#pragma unroll
    for (int i = 0; i < 6; ++i)
        bvv[i] = *(const f32x4*)(bias + (w * 6 + i) * 16 + lq * 4);

    for (int c = 0; c < NCH; ++c) {
        if (L > 0) wait_flag(flag_in, c + 1);          // input chunk ready
        if (c >= 4) wait_flag(flag_seq, c - 3);        // ring back-pressure (4 slots)

        f16* slot = preL + (size_t)(c & 3) * SLOT_H;
#pragma unroll 1
        for (int sc = 0; sc < CH; ++sc) {
            const int t = c * CH + sc;
            f32x4 acc[6];
#pragma unroll
            for (int i = 0; i < 6; ++i) acc[i] = bvv[i];

            const f16* ar = in_seq + (size_t)(t * 16 + lr) * KIN + lq * 8;
            f16x8 a[NK];
#pragma unroll
            for (int kk = 0; kk < NK; ++kk) a[kk] = ld_llc(ar + kk * 32);
            if constexpr (NK == 12) {
                VWAIT4(8, a[0], a[1], a[2], a[3]);
#pragma unroll
                for (int kk = 0; kk < 4; ++kk)
#pragma unroll
                    for (int i = 0; i < 6; ++i) acc[i] = MFMA16(WiF[i][kk], a[kk], acc[i]);
                VWAIT4(4, a[4], a[5], a[6], a[7]);
#pragma unroll
                for (int kk = 4; kk < 8; ++kk)
#pragma unroll
                    for (int i = 0; i < 6; ++i) acc[i] = MFMA16(WiF[i][kk], a[kk], acc[i]);
                VWAIT4(0, a[8], a[9], a[10], a[11]);
#pragma unroll
                for (int kk = 8; kk < 12; ++kk)
#pragma unroll
                    for (int i = 0; i < 6; ++i) acc[i] = MFMA16(WiF[i][kk], a[kk], acc[i]);
            } else {
                VWAIT4(4, a[0], a[1], a[2], a[3]);
#pragma unroll
                for (int kk = 0; kk < 4; ++kk)
#pragma unroll
                    for (int i = 0; i < 6; ++i) acc[i] = MFMA16(WiF[i][kk], a[kk], acc[i]);
                VWAIT4(0, a[4], a[5], a[6], a[7]);
#pragma unroll
                for (int kk = 4; kk < 8; ++kk)
#pragma unroll
                    for (int i = 0; i < 6; ++i) acc[i] = MFMA16(WiF[i][kk], a[kk], acc[i]);
            }
            // f16 pre, CACHED store (release orders it); blob addr same as r14
#pragma unroll
            for (int i = 0; i < 6; ++i) {
                f16x4 ph = { (f16)acc[i][0], (f16)acc[i][1], (f16)acc[i][2], (f16)acc[i][3] };
                *(f16x4*)(slot + ((size_t)(sc * 24 + w * 6 + i) * 64 + lane) * 4) = ph;
            }
        }
        set_flag(flag_pre, c + 1);
    }
}

// ---------------- B-role: recurrence, Wh register-resident ----------------
// SWAPPED MFMA: acc[i][r] = h_pre[n=tile*16+lq*4+r][token=lr] => h write is
// 6x ds_write_b64 (was 24 scalar ds_write_b16 => 737K bank conflicts).
__device__ __forceinline__ void b_role(const f16* __restrict__ preL,
                                       const f16* __restrict__ Wh,
                                       f16* __restrict__ out_seq,
                                       const int* flag_pre, int* flag_seq,
                                       f16 (*hbuf)[16][392]) {
    const int tid = threadIdx.x, lane = tid & 63, w = tid >> 6;
    const int lr = lane & 15, lq = lane >> 4, kb = lq * 8;

    for (int i = tid; i < 2 * 16 * 392; i += 256) (&hbuf[0][0][0])[i] = (f16)0.0f;

    f16x8 WhF[6][12];
#pragma unroll
    for (int i = 0; i < 6; ++i) {
        const f16* wrow = Wh + (size_t)((w * 6 + i) * 16 + lr) * 384 + kb;
#pragma unroll
        for (int kk = 0; kk < 12; ++kk) WhF[i][kk] = *(const f16x8*)(wrow + kk * 32);
    }
    __syncthreads();

    const int crow = tid >> 4;            // cooperative copy coords
    const int ccol = (tid & 15) * 8;

    for (int c = 0; c < NCH; ++c) {
        wait_flag(flag_pre, c + 1);
        const f16* slot = preL + (size_t)(c & 3) * SLOT_H;

#pragma unroll 1
        for (int g = 0; g < CH / 4; ++g) {
            f16x4 pr[4][6];
#pragma unroll
            for (int s = 0; s < 4; ++s)
#pragma unroll
                for (int i = 0; i < 6; ++i)
                    pr[s][i] = ld_llc_f16x4(slot + ((size_t)((g * 4 + s) * 24 + w * 6 + i) * 64 + lane) * 4);
            VWAITH6(0, pr[0][0], pr[0][1], pr[0][2], pr[0][3], pr[0][4], pr[0][5]);
            VWAITH6(0, pr[1][0], pr[1][1], pr[1][2], pr[1][3], pr[1][4], pr[1][5]);
            VWAITH6(0, pr[2][0], pr[2][1], pr[2][2], pr[2][3], pr[2][4], pr[2][5]);
            VWAITH6(0, pr[3][0], pr[3][1], pr[3][2], pr[3][3], pr[3][4], pr[3][5]);

#pragma unroll
            for (int s4 = 0; s4 < 4; ++s4) {
                const int sc = g * 4 + s4;            // step within chunk
                const int t = c * CH + sc;            // t&1 == sc&1 (CH even)
                f32x4 acc[6];
#pragma unroll
                for (int i = 0; i < 6; ++i) acc[i] = (f32x4){ 0.f, 0.f, 0.f, 0.f };

                const f16* hb = &hbuf[sc & 1][0][0] + lr * 392 + kb;
#pragma unroll
                for (int kk = 0; kk < 12; ++kk) {
                    const f16x8 a = *(const f16x8*)(hb + kk * 32);
#pragma unroll
                    for (int i = 0; i < 6; ++i) acc[i] = MFMA16(WhF[i][kk], a, acc[i]);
                }

                // h[token=lr][n = tile*16 + lq*4 + r] : 6x f16x4 = ds_write_b64
                f16* hn = &hbuf[(sc + 1) & 1][0][0] + lr * 392 + lq * 4;
#pragma unroll
                for (int i = 0; i < 6; ++i) {
                    f16x4 hv;
#pragma unroll
                    for (int r = 0; r < 4; ++r)
                        hv[r] = (f16)fast_tanh(acc[i][r] + (float)pr[s4][i][r]);
                    *(f16x4*)(hn + (w * 6 + i) * 16) = hv;
                }
                lds_barrier();   // LDS-only: seq stores below keep flying
                const f16* hs = &hbuf[(sc + 1) & 1][0][0] + crow * 392 + ccol;
                f16* og = out_seq + (size_t)(t * 16 + crow) * 384 + ccol;
#pragma unroll
                for (int p = 0; p < 3; ++p)
                    *(f16x8*)(og + p * 128) = *(const f16x8*)(hs + p * 128);  // CACHED
            }
        }
        set_flag(flag_seq, c + 1);   // barrier + RELEASE (orders the cached seq stores)
    }
}

// ---------------- persistent pipeline: 12 blocks (6 A-role + 6 B-role) ----------------
__global__ __launch_bounds__(256, 1) void pipeline_kernel(
    const f16* __restrict__ seq0, const f16* __restrict__ Wi0,
    const f16* __restrict__ WiR, const f16* __restrict__ WhAll,
    const float* __restrict__ biasAll, f16* __restrict__ sA, f16* __restrict__ sB,
    f16* __restrict__ preRing, int* __restrict__ flags) {
    __shared__ f16 hbuf[2][16][392];
    const int bid = blockIdx.x;
    // flags[0..5] = seq chunks published by layer l; flags[8..13] = pre chunks published
    if (bid < 6) {
        const int L = bid;
        const f16* in_seq = (L == 0) ? seq0 : ((L & 1) ? sA : sB);
        const f16* Wi = (L == 0) ? Wi0 : (WiR + (size_t)(L - 1) * 384 * 384);
        f16* preL = preRing + (size_t)L * 4 * SLOT_H;
        if (L == 0)
            a_role<8>(in_seq, Wi, biasAll, preL, nullptr, flags + 8, flags + 0, 0);
        else
            a_role<12>(in_seq, Wi, biasAll + L * 384, preL, flags + (L - 1), flags + 8 + L, flags + L, L);
    } else {
        const int L = bid - 6;
        f16* outb = (L & 1) ? sB : sA;
        b_role(preRing + (size_t)L * 4 * SLOT_H, WhAll + (size_t)L * 384 * 384, outb,
               flags + 8 + L, flags + L, hbuf);
    }
}

// ---------------- output projection: [8192x384] x [384x32000] + bias ----------------
// 1D grid 16000 = 64 bm x 250 bn, bijective XCD swizzle (bm fastest => Wout tile
// L2-resident). Double-buffered LDS (1 barrier/iter) + SWAPPED-operand MFMA
// (D rows = n) => f32x4 epilogue stores. (r14-verbatim, passing)
__global__ __launch_bounds__(256) void out_proj_kernel(
    const f16* __restrict__ A, const f16* __restrict__ Bm,
    const float* __restrict__ bias, float* __restrict__ C) {
    __shared__ f16 As[2][128][40];
    __shared__ f16 Bs[2][128][40];
    const int tid = threadIdx.x, lane = tid & 63, w = tid >> 6;
    const int lr = lane & 15, lq = lane >> 4;
    const int lin = blockIdx.x;
    const int swz = (lin & 7) * 2000 + (lin >> 3);
    const int bn = swz >> 6;    // 0..249
    const int bm = swz & 63;    // 0..63
    const int wm = w >> 1, wn = w & 1;

    f32x4 acc[4][4];   // [mi][ni]; D row-space = n (swapped operands)
#pragma unroll
    for (int i = 0; i < 4; ++i)
#pragma unroll
        for (int j = 0; j < 4; ++j) acc[i][j] = (f32x4){ 0.f, 0.f, 0.f, 0.f };

    const int sr = tid >> 1, sh = tid & 1;
    const f16* Ag = A + (size_t)(bm * 128 + sr) * 384 + sh * 16;
    const f16* Bg = Bm + (size_t)(bn * 128 + sr) * 384 + sh * 16;

    // prologue: load kt=0 tile to regs
    f16x8 a0 = *(const f16x8*)(Ag);
    f16x8 a1 = *(const f16x8*)(Ag + 8);
    f16x8 b0 = *(const f16x8*)(Bg);
    f16x8 b1 = *(const f16x8*)(Bg + 8);

#pragma unroll 1
    for (int kt = 0; kt < 12; ++kt) {
        const int cur = kt & 1;
        *(f16x8*)(&As[cur][sr][sh * 16]) = a0;
        *(f16x8*)(&As[cur][sr][sh * 16 + 8]) = a1;
        *(f16x8*)(&Bs[cur][sr][sh * 16]) = b0;
        *(f16x8*)(&Bs[cur][sr][sh * 16 + 8]) = b1;
        if (kt < 11) {   // issue next tile's global loads; land after the barrier
            a0 = *(const f16x8*)(Ag + (kt + 1) * 32);
            a1 = *(const f16x8*)(Ag + (kt + 1) * 32 + 8);
            b0 = *(const f16x8*)(Bg + (kt + 1) * 32);
            b1 = *(const f16x8*)(Bg + (kt + 1) * 32 + 8);
        }
        __syncthreads();   // single barrier per iteration (double-buffered LDS)
        f16x8 af[4], bf[4];
#pragma unroll
        for (int mi = 0; mi < 4; ++mi) af[mi] = *(const f16x8*)(&As[cur][wm * 64 + mi * 16 + lr][lq * 8]);
#pragma unroll
        for (int ni = 0; ni < 4; ++ni) bf[ni] = *(const f16x8*)(&Bs[cur][wn * 64 + ni * 16 + lr][lq * 8]);
#pragma unroll
        for (int mi = 0; mi < 4; ++mi)
#pragma unroll
            for (int ni = 0; ni < 4; ++ni)
                acc[mi][ni] = MFMA16(bf[ni], af[mi], acc[mi][ni]);   // SWAPPED: rows=n
    }

    f32x4 bvv[4];
#pragma unroll
    for (int ni = 0; ni < 4; ++ni)
        bvv[ni] = *(const f32x4*)(bias + bn * 128 + wn * 64 + ni * 16 + lq * 4);
#pragma unroll
    for (int mi = 0; mi < 4; ++mi) {
        const int m = bm * 128 + wm * 64 + mi * 16 + lr;   // token = s*16+b
        const int s = m >> 4, b = m & 15;
        float* crow = C + (size_t)(b * 512 + s) * 32000;
#pragma unroll
        for (int ni = 0; ni < 4; ++ni) {
            const int n = bn * 128 + wn * 64 + ni * 16 + lq * 4;
            f32x4 o = acc[mi][ni] + bvv[ni];
            *(f32x4*)(crow + n) = o;
        }
    }
}

extern "C" void kernel_launch(void* const* d_in, const int* in_sizes, int n_in,
                              void* d_out, int out_size, void* d_ws, size_t ws_size,
                              hipStream_t stream) {
    const int* x = (const int*)d_in[0];
    const float* emb = (const float*)d_in[1];
    const float* W_ih0 = (const float*)d_in[2];
    const float* W_ih = (const float*)d_in[3];
    const float* W_hh = (const float*)d_in[4];
    const float* b_ih = (const float*)d_in[5];
    const float* b_hh = (const float*)d_in[6];
    const float* W_out = (const float*)d_in[7];
    const float* b_out = (const float*)d_in[8];
    float* out = (float*)d_out;

    // workspace layout (bytes)
    char* ws = (char*)d_ws;
    f16* Wi0_h = (f16*)(ws + 0);              //   384*256*2 = 196608
    f16* Wi_h = (f16*)(ws + 196608);          // 5*384*384*2 = 1474560
    f16* Wh_h = (f16*)(ws + 1671168);         // 6*384*384*2 = 1769472
    f16* Wout_h = (f16*)(ws + 3440640);       // 32000*384*2 = 24576000
    float* bias_c = (float*)(ws + 28016640);  // 6*384*4 = 9216
    f16* seq0 = (f16*)(ws + 28025856);        // 8192*256*2 = 4194304
    f16* sA = (f16*)(ws + 32220160);          // 8192*384*2 = 6291456
    f16* sB = (f16*)(ws + 38511616);          // 8192*384*2 = 6291456
    f16* preRing = (f16*)(ws + 44803072);     // 6*4*98304*2 = 4718592
    int* flags = (int*)(ws + 49521664);       // 256 -> end 49521920
    if (ws_size < 49521920u) return;

    hipMemsetAsync(flags, 0, 256, stream);
    cvt_kernel<<<96, 256, 0, stream>>>(W_ih0, Wi0_h, 24576);
    cvt_kernel<<<720, 256, 0, stream>>>(W_ih, Wi_h, 184320);
    cvt_kernel<<<864, 256, 0, stream>>>(W_hh, Wh_h, 221184);
    cvt_kernel<<<12000, 256, 0, stream>>>(W_out, Wout_h, 3072000);
    bias_combine_kernel<<<9, 256, 0, stream>>>(b_ih, b_hh, bias_c);
    embed_kernel<<<8192, 64, 0, stream>>>(x, emb, seq0);

    pipeline_kernel<<<12, 256, 0, stream>>>(seq0, Wi0_h, Wi_h, Wh_h, bias_c,
                                            sA, sB, preRing, flags);

    out_proj_kernel<<<16000, 256, 0, stream>>>(sB, Wout_h, b_out, out);
}